// Round 3
// baseline (495.723 us; speedup 1.0000x reference)
//
#include <hip/hip_runtime.h>
#include <stdint.h>

#pragma clang fp contract(off)

typedef unsigned long long u64;
typedef unsigned int u32;

#define NH 192
#define NW 192
#define NK 9
#define NPB (NH * NW * NK)   // 331776 anchors per batch
#define PRE_NMS 2048
#define CAP 4096             // compacted-candidate capacity per batch
#define FAST_CAP 512         // fast-path sorted-prefix capacity
#define FAST_K 256           // fast-path target prefix size
#define MOS 100
#define SCORE_T_BITS 0x3F666666u   // float bits of 0.9f (scores in [0,1) -> positive)
#define IOU_T 0.9f

// ws layout: hist B*256 int | cnt B int | bound B u32 | keys B*CAP u64

__global__ void zero_meta(int* __restrict__ meta, int n) {
    int i = blockIdx.x * blockDim.x + threadIdx.x;
    if (i < n) meta[i] = 0;
}

// Histogram of (bits>>16)&0xFF for scores with bits > SCORE_T_BITS.
// grid (81, B), block 256; each thread 4x uint4 = 16 scores.
__global__ void hist_kernel(const uint4* __restrict__ scores, int* __restrict__ hist) {
    __shared__ int lh[256];
    const int t = threadIdx.x;
    lh[t] = 0;
    __syncthreads();
    const int b = blockIdx.y;
    const uint4* sp = scores + (size_t)b * (NPB / 4) + (size_t)blockIdx.x * 1024;
#pragma unroll
    for (int i = 0; i < 4; ++i) {
        uint4 v = sp[t + i * 256];
        if (v.x > SCORE_T_BITS) atomicAdd(&lh[(v.x >> 16) & 0xFF], 1);
        if (v.y > SCORE_T_BITS) atomicAdd(&lh[(v.y >> 16) & 0xFF], 1);
        if (v.z > SCORE_T_BITS) atomicAdd(&lh[(v.z >> 16) & 0xFF], 1);
        if (v.w > SCORE_T_BITS) atomicAdd(&lh[(v.w >> 16) & 0xFF], 1);
    }
    __syncthreads();
    if (lh[t] != 0) atomicAdd(&hist[b * 256 + t], lh[t]);
}

// Per batch: bucket where descending cumulative count crosses PRE_NMS, folded
// with score>0.9 into a single uint lower bound on score bits.
__global__ void thresh_kernel(const int* __restrict__ hist, u32* __restrict__ bound, int B) {
    int b = blockIdx.x * blockDim.x + threadIdx.x;
    if (b < B) {
        int cum = 0, tv = 0;
        for (int v = 255; v >= 0; --v) {
            cum += hist[b * 256 + v];
            if (cum >= PRE_NMS) { tv = v; break; }
        }
        u32 bd = ((u32)(0x3F00 + tv)) << 16;
        if (bd < SCORE_T_BITS + 1) bd = SCORE_T_BITS + 1;
        bound[b] = bd;
    }
}

// Compact candidates with bits >= bound into keys (score_bits<<32)|~idx.
__global__ void compact_kernel(const uint4* __restrict__ scores,
                               const u32* __restrict__ bound,
                               int* __restrict__ cnt,
                               u64* __restrict__ keys) {
    __shared__ u64 stage[4096];
    __shared__ int lcount, lbase;
    const int t = threadIdx.x;
    if (t == 0) lcount = 0;
    __syncthreads();
    const int b = blockIdx.y;
    const u32 bd = bound[b];
    const int base_i = blockIdx.x * 4096;
    const uint4* sp = scores + (size_t)b * (NPB / 4) + (size_t)blockIdx.x * 1024;
#pragma unroll
    for (int i = 0; i < 4; ++i) {
        uint4 v = sp[t + i * 256];
        int ei = base_i + (t + i * 256) * 4;
        u32 uu[4] = {v.x, v.y, v.z, v.w};
#pragma unroll
        for (int c = 0; c < 4; ++c) {
            if (uu[c] >= bd) {
                int p = atomicAdd(&lcount, 1);
                u32 idx = (u32)(ei + c);
                stage[p] = ((u64)uu[c] << 32) | (u64)(~idx);
            }
        }
    }
    __syncthreads();
    if (t == 0) lbase = atomicAdd(&cnt[b], lcount);
    __syncthreads();
    const int nb = lcount, gb = lbase;
    u64* kb = keys + (size_t)b * CAP;
    for (int i = t; i < nb; i += 256) {
        int gp = gb + i;
        if (gp < CAP) kb[gp] = stage[i];
    }
}

__device__ __forceinline__ float4 decode_box(u64 key, int b,
                                             const float4* __restrict__ anchors4,
                                             const float4* __restrict__ deltas4) {
    u32 idx = ~(u32)(key & 0xFFFFFFFFu);
    float4 a = anchors4[idx];                       // [xmin,xmax,ymin,ymax]
    float4 d = deltas4[(size_t)b * NPB + idx];      // [tx,ty,tw,th]
    float xa = (a.x + a.y) * 0.5f;
    float ya = (a.z + a.w) * 0.5f;
    float wa = a.y - a.x;
    float ha = a.w - a.z;
    float x = d.x * wa + xa;
    float y = d.y * ha + ya;
    float w = expf(d.z) * wa;
    float h = expf(d.w) * ha;
    float4 bx;
    bx.x = fminf(y + h * 0.5f, 1.f);   // ymax
    bx.y = fmaxf(x - w * 0.5f, 0.f);   // xmin
    bx.z = fmaxf(y - h * 0.5f, 0.f);   // ymin
    bx.w = fminf(x + w * 0.5f, 1.f);   // xmax
    return bx;
}

// Wave-level candidate-form greedy NMS: box j is picked iff IoU(j, p) <= T for
// all earlier picks p (equivalent to reference argmax/suppress by induction).
// Picks live 2/lane in registers; writes picks to out4 as found; returns np.
__device__ __forceinline__ int wave_nms(const float4* __restrict__ boxes, int n,
                                        float4* __restrict__ out4, int lane) {
    float4 pb0 = make_float4(0.f, 0.f, 0.f, 0.f), pb1 = pb0;
    float pa0 = 0.f, pa1 = 0.f;
    int np = 0;
    for (int j = 0; j < n; ++j) {
        float4 cb = boxes[j];   // LDS same-address broadcast
        float areab = fmaxf(cb.x - cb.z, 0.f) * fmaxf(cb.w - cb.y, 0.f);
        bool sup = false;
        if (lane < np) {
            float ih = fmaxf(fminf(pb0.x, cb.x) - fmaxf(pb0.z, cb.z), 0.f);
            float iw = fmaxf(fminf(pb0.w, cb.w) - fmaxf(pb0.y, cb.y), 0.f);
            float inter = ih * iw;
            sup = inter / (pa0 + areab - inter + 1e-9f) > IOU_T;
        }
        if (lane + 64 < np) {
            float ih = fmaxf(fminf(pb1.x, cb.x) - fmaxf(pb1.z, cb.z), 0.f);
            float iw = fmaxf(fminf(pb1.w, cb.w) - fmaxf(pb1.y, cb.y), 0.f);
            float inter = ih * iw;
            sup = sup || (inter / (pa1 + areab - inter + 1e-9f) > IOU_T);
        }
        if (!__any(sup)) {
            if (lane == (np & 63)) {
                if (np < 64) { pb0 = cb; pa0 = areab; }
                else         { pb1 = cb; pa1 = areab; }
                out4[np] = cb;
            }
            if (++np == MOS) break;
        }
    }
    return np;
}

// One block (256 thr) per batch. Fast path: refine an in-LDS score-bit bound
// capturing the top >=FAST_K (<=FAST_CAP) keys — an exact prefix of the global
// descending order — sort only those, decode, wave-0 NMS. Fallback (never for
// this data, kept for construction-correctness): full 4096 sort + 2048 decode.
__global__ __launch_bounds__(256) void sort_nms_kernel(
        const float* __restrict__ deltas, const float* __restrict__ anchors,
        const int* __restrict__ cnt, const u64* __restrict__ keys,
        float* __restrict__ out) {
    __shared__ __align__(16) u64 key_s[CAP];         // 32 KB
    __shared__ __align__(16) float4 boxes[PRE_NMS];  // 32 KB
    __shared__ u64 fast_k[FAST_CAP];                 // 4 KB
    __shared__ int lh[256];
    __shared__ int s_cnt, s_nsel, s_flag;
    __shared__ u32 s_bound;

    const int t = threadIdx.x;
    const int b = blockIdx.x;
    const int nc = min(cnt[b], CAP);
    const u64* kb = keys + (size_t)b * CAP;
    const float4* anchors4 = (const float4*)anchors;
    const float4* deltas4  = (const float4*)deltas;
    float4* out4 = (float4*)out + (size_t)b * MOS;

    lh[t] = 0;
    if (t == 0) s_cnt = 0;
    __syncthreads();

    // Load keys + histogram hi-bits (hi>>15)&0xFF (valid bins 0xCC..0xFF).
#pragma unroll
    for (int p = 0; p < CAP / 256; ++p) {
        int i = t + p * 256;
        u64 k = (i < nc) ? kb[i] : 0ULL;
        key_s[i] = k;
        if (i < nc) atomicAdd(&lh[(u32)(k >> 47) & 0xFF], 1);
    }
    for (int i = t; i < FAST_CAP; i += 256) fast_k[i] = 0ULL;
    __syncthreads();

    // Pick refined bound: smallest suffix with count >= FAST_K (<= FAST_CAP).
    if (t == 0) {
        int cum = 0, chosen = -1;
        for (int v = 255; v >= 0; --v) {
            cum += lh[v];
            if (cum >= FAST_K) { chosen = v; break; }
        }
        if (chosen < 0)                { s_bound = 0u; s_nsel = nc; }
        else if (cum > FAST_CAP)       { s_bound = ((0x7E00u | (u32)(chosen + 1)) << 15);
                                         s_nsel = cum - lh[chosen]; }
        else                           { s_bound = ((0x7E00u | (u32)chosen) << 15);
                                         s_nsel = cum; }
    }
    __syncthreads();
    const u32 bsel = s_bound;

    // Compact the selected prefix set into fast_k (order fixed by the sort).
#pragma unroll
    for (int p = 0; p < CAP / 256; ++p) {
        int i = t + p * 256;
        if (i < nc) {
            u64 k = key_s[i];
            if ((u32)(k >> 32) >= bsel) fast_k[atomicAdd(&s_cnt, 1)] = k;
        }
    }
    __syncthreads();
    const int n_sel = s_nsel;

    // Bitonic sort fast_k[512] desc (unique nonzero keys; pads sink to tail).
    for (int k = 2; k <= FAST_CAP; k <<= 1) {
        for (int j = k >> 1; j > 0; j >>= 1) {
            for (int i = t; i < FAST_CAP; i += 256) {
                int ix = i ^ j;
                if (ix > i) {
                    u64 a = fast_k[i], c = fast_k[ix];
                    bool up = ((i & k) == 0);
                    if (up ? (a < c) : (a > c)) { fast_k[i] = c; fast_k[ix] = a; }
                }
            }
            __syncthreads();
        }
    }

    // Decode fast prefix.
    for (int i = t; i < FAST_CAP; i += 256)
        boxes[i] = (i < n_sel) ? decode_box(fast_k[i], b, anchors4, deltas4)
                               : make_float4(0.f, 0.f, 0.f, 0.f);
    __syncthreads();

    if (t < 64) {
        int np = wave_nms(boxes, n_sel, out4, t);
        bool success = (np == MOS) || (n_sel == nc);
        if (success)
            for (int i = np + t; i < MOS; i += 64)
                out4[i] = make_float4(0.f, 0.f, 0.f, 0.f);
        if (t == 0) s_flag = success ? 1 : 0;
    }
    __syncthreads();
    if (s_flag) return;

    // ---------- Fallback: exact full path (rare by data, required by rigor) --
    for (int k = 2; k <= CAP; k <<= 1) {
        for (int j = k >> 1; j > 0; j >>= 1) {
            for (int i = t; i < CAP; i += 256) {
                int ix = i ^ j;
                if (ix > i) {
                    u64 a = key_s[i], c = key_s[ix];
                    bool up = ((i & k) == 0);
                    if (up ? (a < c) : (a > c)) { key_s[i] = c; key_s[ix] = a; }
                }
            }
            __syncthreads();
        }
    }
    const int nvalid = min(nc, PRE_NMS);
    for (int i = t; i < PRE_NMS; i += 256)
        boxes[i] = (i < nvalid) ? decode_box(key_s[i], b, anchors4, deltas4)
                                : make_float4(0.f, 0.f, 0.f, 0.f);
    __syncthreads();
    if (t < 64) {
        int np = wave_nms(boxes, nvalid, out4, t);
        for (int i = np + t; i < MOS; i += 64)
            out4[i] = make_float4(0.f, 0.f, 0.f, 0.f);
    }
}

extern "C" void kernel_launch(void* const* d_in, const int* in_sizes, int n_in,
                              void* d_out, int out_size, void* d_ws, size_t ws_size,
                              hipStream_t stream) {
    const float* score_map = (const float*)d_in[0];
    const float* delta_map = (const float*)d_in[1];
    const float* anchors   = (const float*)d_in[2];
    float* out = (float*)d_out;
    const int B = in_sizes[0] / NPB;   // 32

    char* ws = (char*)d_ws;
    int* hist  = (int*)ws;                                         // B*256 ints
    int* cnt   = (int*)(ws + (size_t)B * 256 * 4);                 // B ints
    u32* bound = (u32*)(ws + (size_t)B * 256 * 4 + (size_t)B * 4); // B u32
    u64* keys  = (u64*)(ws + (size_t)B * 256 * 4 + 2 * (size_t)B * 4); // B*CAP u64

    const int meta_n = B * 256 + B;   // hist + cnt
    zero_meta<<<(meta_n + 255) / 256, 256, 0, stream>>>(hist, meta_n);
    hist_kernel<<<dim3(NPB / 4096, B), 256, 0, stream>>>((const uint4*)score_map, hist);
    thresh_kernel<<<1, 256, 0, stream>>>(hist, bound, B);
    compact_kernel<<<dim3(NPB / 4096, B), 256, 0, stream>>>((const uint4*)score_map, bound, cnt, keys);
    sort_nms_kernel<<<B, 256, 0, stream>>>(delta_map, anchors, cnt, keys, out);
}

// Round 4
// 324.041 us; speedup vs baseline: 1.5298x; 1.5298x over previous
//
#include <hip/hip_runtime.h>
#include <stdint.h>

#pragma clang fp contract(off)

typedef unsigned long long u64;
typedef unsigned int u32;

#define NH 192
#define NW 192
#define NK 9
#define NPB (NH * NW * NK)   // 331776 anchors per batch
#define PRE_NMS 2048
#define CAP 4096             // compacted-candidate capacity per batch
#define FAST_CAP 512         // fast-path sorted-prefix capacity
#define FAST_K 256           // fast-path target prefix size
#define MOS 100
#define SCORE_T_BITS 0x3F666666u   // float bits of 0.9f (scores in [0,1) -> positive)
#define ONE_BITS 0x3F800000u       // float bits of 1.0f
#define IOU_T 0.9f

// ws layout: hist B*256 int | cnt B int | bound B u32 | keys B*CAP u64

__global__ void zero_meta(int* __restrict__ meta, int n) {
    int i = blockIdx.x * blockDim.x + threadIdx.x;
    if (i < n) meta[i] = 0;
}

// Histogram of (bits>>16)&0xFF for scores with bits > SCORE_T_BITS.
__global__ void hist_kernel(const uint4* __restrict__ scores, int* __restrict__ hist) {
    __shared__ int lh[256];
    const int t = threadIdx.x;
    lh[t] = 0;
    __syncthreads();
    const int b = blockIdx.y;
    const uint4* sp = scores + (size_t)b * (NPB / 4) + (size_t)blockIdx.x * 1024;
#pragma unroll
    for (int i = 0; i < 4; ++i) {
        uint4 v = sp[t + i * 256];
        if (v.x > SCORE_T_BITS) atomicAdd(&lh[(v.x >> 16) & 0xFF], 1);
        if (v.y > SCORE_T_BITS) atomicAdd(&lh[(v.y >> 16) & 0xFF], 1);
        if (v.z > SCORE_T_BITS) atomicAdd(&lh[(v.z >> 16) & 0xFF], 1);
        if (v.w > SCORE_T_BITS) atomicAdd(&lh[(v.w >> 16) & 0xFF], 1);
    }
    __syncthreads();
    if (lh[t] != 0) atomicAdd(&hist[b * 256 + t], lh[t]);
}

// Per batch: bucket where descending cumulative count crosses PRE_NMS, folded
// with score>0.9 into a single uint lower bound on score bits.
__global__ void thresh_kernel(const int* __restrict__ hist, u32* __restrict__ bound, int B) {
    int b = blockIdx.x * blockDim.x + threadIdx.x;
    if (b < B) {
        int cum = 0, tv = 0;
        for (int v = 255; v >= 0; --v) {
            cum += hist[b * 256 + v];
            if (cum >= PRE_NMS) { tv = v; break; }
        }
        u32 bd = ((u32)(0x3F00 + tv)) << 16;
        if (bd < SCORE_T_BITS + 1) bd = SCORE_T_BITS + 1;
        bound[b] = bd;
    }
}

// Compact candidates with bits >= bound into keys (score_bits<<32)|~idx.
__global__ void compact_kernel(const uint4* __restrict__ scores,
                               const u32* __restrict__ bound,
                               int* __restrict__ cnt,
                               u64* __restrict__ keys) {
    __shared__ u64 stage[4096];
    __shared__ int lcount, lbase;
    const int t = threadIdx.x;
    if (t == 0) lcount = 0;
    __syncthreads();
    const int b = blockIdx.y;
    const u32 bd = bound[b];
    const int base_i = blockIdx.x * 4096;
    const uint4* sp = scores + (size_t)b * (NPB / 4) + (size_t)blockIdx.x * 1024;
#pragma unroll
    for (int i = 0; i < 4; ++i) {
        uint4 v = sp[t + i * 256];
        int ei = base_i + (t + i * 256) * 4;
        u32 uu[4] = {v.x, v.y, v.z, v.w};
#pragma unroll
        for (int c = 0; c < 4; ++c) {
            if (uu[c] >= bd) {
                int p = atomicAdd(&lcount, 1);
                u32 idx = (u32)(ei + c);
                stage[p] = ((u64)uu[c] << 32) | (u64)(~idx);
            }
        }
    }
    __syncthreads();
    if (t == 0) lbase = atomicAdd(&cnt[b], lcount);
    __syncthreads();
    const int nb = lcount, gb = lbase;
    u64* kb = keys + (size_t)b * CAP;
    for (int i = t; i < nb; i += 256) {
        int gp = gb + i;
        if (gp < CAP) kb[gp] = stage[i];
    }
}

__device__ __forceinline__ float4 decode_box(u64 key, int b,
                                             const float4* __restrict__ anchors4,
                                             const float4* __restrict__ deltas4) {
    u32 idx = ~(u32)(key & 0xFFFFFFFFu);
    float4 a = anchors4[idx];                       // [xmin,xmax,ymin,ymax]
    float4 d = deltas4[(size_t)b * NPB + idx];      // [tx,ty,tw,th]
    float xa = (a.x + a.y) * 0.5f;
    float ya = (a.z + a.w) * 0.5f;
    float wa = a.y - a.x;
    float ha = a.w - a.z;
    float x = d.x * wa + xa;
    float y = d.y * ha + ya;
    float w = expf(d.z) * wa;
    float h = expf(d.w) * ha;
    float4 bx;
    bx.x = fminf(y + h * 0.5f, 1.f);   // ymax
    bx.y = fmaxf(x - w * 0.5f, 0.f);   // xmin
    bx.z = fmaxf(y - h * 0.5f, 0.f);   // ymin
    bx.w = fminf(x + w * 0.5f, 1.f);   // xmax
    return bx;
}

// Wave-level candidate-form greedy NMS: box j is picked iff IoU(j, p) <= T for
// all earlier picks p (equivalent to reference argmax/suppress by induction).
// Picks live 2/lane in registers; writes picks to out4 as found; returns np.
__device__ __forceinline__ int wave_nms(const float4* __restrict__ boxes, int n,
                                        float4* __restrict__ out4, int lane) {
    float4 pb0 = make_float4(0.f, 0.f, 0.f, 0.f), pb1 = pb0;
    float pa0 = 0.f, pa1 = 0.f;
    int np = 0;
    float4 nxt = boxes[0];   // LDS same-address broadcast, prefetched
    for (int j = 0; j < n; ++j) {
        float4 cb = nxt;
        nxt = boxes[(j + 1 < n) ? (j + 1) : j];
        float areab = fmaxf(cb.x - cb.z, 0.f) * fmaxf(cb.w - cb.y, 0.f);
        bool sup = false;
        if (lane < np) {
            float ih = fmaxf(fminf(pb0.x, cb.x) - fmaxf(pb0.z, cb.z), 0.f);
            float iw = fmaxf(fminf(pb0.w, cb.w) - fmaxf(pb0.y, cb.y), 0.f);
            float inter = ih * iw;
            sup = inter / (pa0 + areab - inter + 1e-9f) > IOU_T;
        }
        if (lane + 64 < np) {
            float ih = fmaxf(fminf(pb1.x, cb.x) - fmaxf(pb1.z, cb.z), 0.f);
            float iw = fmaxf(fminf(pb1.w, cb.w) - fmaxf(pb1.y, cb.y), 0.f);
            float inter = ih * iw;
            sup = sup || (inter / (pa1 + areab - inter + 1e-9f) > IOU_T);
        }
        if (!__any(sup)) {
            if (lane == (np & 63)) {
                if (np < 64) { pb0 = cb; pa0 = areab; }
                else         { pb1 = cb; pa1 = areab; }
                out4[np] = cb;
            }
            if (++np == MOS) break;
        }
    }
    return np;
}

// One block (256 thr) per batch. Fast path: refine a per-batch bound on
// d = ONE_BITS - score_bits (distance from 1.0), shifted so the compacted
// keys spread over ~128-255 bins, capturing the top >=FAST_K (<=FAST_CAP)
// keys — an exact prefix of the global descending order. Sort those, decode,
// wave-0 NMS. Fallback (never for this data): full 4096 sort + 2048 decode.
__global__ __launch_bounds__(256) void sort_nms_kernel(
        const float* __restrict__ deltas, const float* __restrict__ anchors,
        const int* __restrict__ cnt, const u32* __restrict__ bound,
        const u64* __restrict__ keys, float* __restrict__ out) {
    __shared__ __align__(16) u64 key_s[CAP];         // 32 KB
    __shared__ __align__(16) float4 boxes[PRE_NMS];  // 32 KB
    __shared__ u64 fast_k[FAST_CAP];                 // 4 KB
    __shared__ int lh[256];
    __shared__ int s_cnt, s_nsel, s_flag, s_cbin, s_sh;

    const int t = threadIdx.x;
    const int b = blockIdx.x;
    const int nc = min(cnt[b], CAP);
    const u64* kb = keys + (size_t)b * CAP;
    const float4* anchors4 = (const float4*)anchors;
    const float4* deltas4  = (const float4*)deltas;
    float4* out4 = (float4*)out + (size_t)b * MOS;

    lh[t] = 0;
    if (t == 0) {
        s_cnt = 0;
        u32 dmax = ONE_BITS - bound[b];        // bound <= 0x3F7F0000 < ONE_BITS
        int bits = 32 - __builtin_clz(dmax);   // dmax >= 1
        s_sh = (bits > 8) ? (bits - 8) : 0;
    }
    __syncthreads();
    const int sh = s_sh;

    // Load keys + histogram of distance bins (d >> sh), d = ONE_BITS - hi.
#pragma unroll
    for (int p = 0; p < CAP / 256; ++p) {
        int i = t + p * 256;
        u64 k = (i < nc) ? kb[i] : 0ULL;
        key_s[i] = k;
        if (i < nc) {
            u32 d = ONE_BITS - (u32)(k >> 32);   // hi in [bound, ONE_BITS) -> d in (0, dmax]
            u32 bin = d >> sh;
            if (bin > 255u) bin = 255u;
            atomicAdd(&lh[bin], 1);
        }
    }
    for (int i = t; i < FAST_CAP; i += 256) fast_k[i] = 0ULL;
    __syncthreads();

    // Scan bins from best (0) up: smallest prefix with count >= FAST_K.
    if (t == 0) {
        int cum = 0; bool hit = false;
        for (int v = 0; v < 256; ++v) {
            cum += lh[v];
            if (cum >= FAST_K) {
                if (cum > FAST_CAP) { s_nsel = cum - lh[v]; s_cbin = v - 1; }
                else                { s_nsel = cum;         s_cbin = v; }
                hit = true; break;
            }
        }
        if (!hit) { s_nsel = cum; s_cbin = 255; }   // nc < FAST_K: take all
    }
    __syncthreads();
    const int cbin = s_cbin;
    const int n_sel = s_nsel;

    // Compact the selected prefix set into fast_k (order fixed by the sort).
#pragma unroll
    for (int p = 0; p < CAP / 256; ++p) {
        int i = t + p * 256;
        if (i < nc) {
            u64 k = key_s[i];
            u32 d = ONE_BITS - (u32)(k >> 32);
            u32 bin = d >> sh;
            if (bin > 255u) bin = 255u;
            if ((int)bin <= cbin) fast_k[atomicAdd(&s_cnt, 1)] = k;
        }
    }
    __syncthreads();

    // Bitonic sort fast_k[512] desc (unique nonzero keys; pads sink to tail).
    for (int k = 2; k <= FAST_CAP; k <<= 1) {
        for (int j = k >> 1; j > 0; j >>= 1) {
            for (int i = t; i < FAST_CAP; i += 256) {
                int ix = i ^ j;
                if (ix > i) {
                    u64 a = fast_k[i], c = fast_k[ix];
                    bool up = ((i & k) == 0);
                    if (up ? (a < c) : (a > c)) { fast_k[i] = c; fast_k[ix] = a; }
                }
            }
            __syncthreads();
        }
    }

    // Decode fast prefix.
    for (int i = t; i < FAST_CAP; i += 256)
        boxes[i] = (i < n_sel) ? decode_box(fast_k[i], b, anchors4, deltas4)
                               : make_float4(0.f, 0.f, 0.f, 0.f);
    __syncthreads();

    if (t < 64) {
        int np = wave_nms(boxes, n_sel, out4, t);
        bool success = (np == MOS) || (n_sel == nc);
        if (success)
            for (int i = np + t; i < MOS; i += 64)
                out4[i] = make_float4(0.f, 0.f, 0.f, 0.f);
        if (t == 0) s_flag = success ? 1 : 0;
    }
    __syncthreads();
    if (s_flag) return;

    // ---------- Fallback: exact full path (rare by data, required by rigor) --
    for (int k = 2; k <= CAP; k <<= 1) {
        for (int j = k >> 1; j > 0; j >>= 1) {
            for (int i = t; i < CAP; i += 256) {
                int ix = i ^ j;
                if (ix > i) {
                    u64 a = key_s[i], c = key_s[ix];
                    bool up = ((i & k) == 0);
                    if (up ? (a < c) : (a > c)) { key_s[i] = c; key_s[ix] = a; }
                }
            }
            __syncthreads();
        }
    }
    const int nvalid = min(nc, PRE_NMS);
    for (int i = t; i < PRE_NMS; i += 256)
        boxes[i] = (i < nvalid) ? decode_box(key_s[i], b, anchors4, deltas4)
                                : make_float4(0.f, 0.f, 0.f, 0.f);
    __syncthreads();
    if (t < 64) {
        int np = wave_nms(boxes, nvalid, out4, t);
        for (int i = np + t; i < MOS; i += 64)
            out4[i] = make_float4(0.f, 0.f, 0.f, 0.f);
    }
}

extern "C" void kernel_launch(void* const* d_in, const int* in_sizes, int n_in,
                              void* d_out, int out_size, void* d_ws, size_t ws_size,
                              hipStream_t stream) {
    const float* score_map = (const float*)d_in[0];
    const float* delta_map = (const float*)d_in[1];
    const float* anchors   = (const float*)d_in[2];
    float* out = (float*)d_out;
    const int B = in_sizes[0] / NPB;   // 32

    char* ws = (char*)d_ws;
    int* hist  = (int*)ws;                                         // B*256 ints
    int* cnt   = (int*)(ws + (size_t)B * 256 * 4);                 // B ints
    u32* bound = (u32*)(ws + (size_t)B * 256 * 4 + (size_t)B * 4); // B u32
    u64* keys  = (u64*)(ws + (size_t)B * 256 * 4 + 2 * (size_t)B * 4); // B*CAP u64

    const int meta_n = B * 256 + B;   // hist + cnt
    zero_meta<<<(meta_n + 255) / 256, 256, 0, stream>>>(hist, meta_n);
    hist_kernel<<<dim3(NPB / 4096, B), 256, 0, stream>>>((const uint4*)score_map, hist);
    thresh_kernel<<<1, 256, 0, stream>>>(hist, bound, B);
    compact_kernel<<<dim3(NPB / 4096, B), 256, 0, stream>>>((const uint4*)score_map, bound, cnt, keys);
    sort_nms_kernel<<<B, 256, 0, stream>>>(delta_map, anchors, cnt, bound, keys, out);
}

// Round 5
// 301.000 us; speedup vs baseline: 1.6469x; 1.0765x over previous
//
#include <hip/hip_runtime.h>
#include <stdint.h>

#pragma clang fp contract(off)

typedef unsigned long long u64;
typedef unsigned int u32;

#define NH 192
#define NW 192
#define NK 9
#define NPB (NH * NW * NK)   // 331776 anchors per batch
#define PRE_NMS 2048
#define CAP 4096             // compacted-candidate capacity per batch
#define FAST_CAP 512         // fast-path sorted-prefix capacity
#define FAST_K 256           // fast-path target prefix size
#define MOS 100
#define SCORE_T_BITS 0x3F666666u   // float bits of 0.9f (scores in [0,1) -> positive)
#define SPEC_BITS   0x3F7E0000u    // speculative bound: score >= 0.9921875
                                   // E[cnt]=2592/batch, sigma~51 -> in [2048,4096] w/ >10 sigma
#define ONE_BITS 0x3F800000u       // float bits of 1.0f
#define IOU_T 0.9f

// ws layout: hist B*256 int | cnt B int | bound B u32 | flag B int | keys B*CAP u64

__global__ void zero_meta(int* __restrict__ meta, int n) {
    int i = blockIdx.x * blockDim.x + threadIdx.x;
    if (i < n) meta[i] = 0;
}

// ONE pass over scores: compact bits >= SPEC_BITS into keys (score<<32)|~idx,
// and build the full repair histogram ((bits>>16)&0xFF for bits>SCORE_T) in
// the same read. grid (81,B), block 256, 16 scores/thread.
__global__ void spec_compact_kernel(const uint4* __restrict__ scores,
                                    int* __restrict__ hist,
                                    int* __restrict__ cnt,
                                    u64* __restrict__ keys) {
    __shared__ u64 stage[4096];
    __shared__ int lh[256];
    __shared__ int lcount, lbase;
    const int t = threadIdx.x;
    lh[t] = 0;
    if (t == 0) lcount = 0;
    __syncthreads();
    const int b = blockIdx.y;
    const int base_i = blockIdx.x * 4096;
    const uint4* sp = scores + (size_t)b * (NPB / 4) + (size_t)blockIdx.x * 1024;
#pragma unroll
    for (int i = 0; i < 4; ++i) {
        uint4 v = sp[t + i * 256];
        int ei = base_i + (t + i * 256) * 4;
        u32 uu[4] = {v.x, v.y, v.z, v.w};
#pragma unroll
        for (int c = 0; c < 4; ++c) {
            u32 u = uu[c];
            if (u > SCORE_T_BITS) {
                atomicAdd(&lh[(u >> 16) & 0xFF], 1);
                if (u >= SPEC_BITS) {
                    int p = atomicAdd(&lcount, 1);
                    u32 idx = (u32)(ei + c);
                    stage[p] = ((u64)u << 32) | (u64)(~idx);
                }
            }
        }
    }
    __syncthreads();
    if (t == 0) lbase = atomicAdd(&cnt[b], lcount);
    if (lh[t] != 0) atomicAdd(&hist[b * 256 + t], lh[t]);
    __syncthreads();
    const int nb = lcount, gb = lbase;
    u64* kb = keys + (size_t)b * CAP;
    for (int i = t; i < nb; i += 256) {
        int gp = gb + i;
        if (gp < CAP) kb[gp] = stage[i];
    }
}

// Per batch: accept the speculative set if cnt in [PRE_NMS, CAP] (then it is a
// superset of the exact top-2048); else compute the exact hist-based bound
// (round-4 thresh semantics) and flag the batch for repair.
__global__ void fixup_kernel(const int* __restrict__ hist, int* __restrict__ cnt,
                             u32* __restrict__ bound, int* __restrict__ flag, int B) {
    int b = blockIdx.x * blockDim.x + threadIdx.x;
    if (b >= B) return;
    int c = cnt[b];
    if (c >= PRE_NMS && c <= CAP) { bound[b] = SPEC_BITS; flag[b] = 0; return; }
    int cum = 0, tv = 0;
    for (int v = 255; v >= 0; --v) {
        cum += hist[b * 256 + v];
        if (cum >= PRE_NMS) { tv = v; break; }
    }
    u32 bd = ((u32)(0x3F00 + tv)) << 16;
    if (bd < SCORE_T_BITS + 1) bd = SCORE_T_BITS + 1;
    bound[b] = bd; flag[b] = 1; cnt[b] = 0;
}

// Repair pass (early-exit when the speculative set was accepted — the common
// case costs only the launch). Identical semantics to the round-4 compact.
__global__ void repair_compact_kernel(const uint4* __restrict__ scores,
                                      const u32* __restrict__ bound,
                                      const int* __restrict__ flag,
                                      int* __restrict__ cnt,
                                      u64* __restrict__ keys) {
    const int b = blockIdx.y;
    if (!flag[b]) return;     // uniform per block
    __shared__ u64 stage[4096];
    __shared__ int lcount, lbase;
    const int t = threadIdx.x;
    if (t == 0) lcount = 0;
    __syncthreads();
    const u32 bd = bound[b];
    const int base_i = blockIdx.x * 4096;
    const uint4* sp = scores + (size_t)b * (NPB / 4) + (size_t)blockIdx.x * 1024;
#pragma unroll
    for (int i = 0; i < 4; ++i) {
        uint4 v = sp[t + i * 256];
        int ei = base_i + (t + i * 256) * 4;
        u32 uu[4] = {v.x, v.y, v.z, v.w};
#pragma unroll
        for (int c = 0; c < 4; ++c) {
            if (uu[c] >= bd) {
                int p = atomicAdd(&lcount, 1);
                u32 idx = (u32)(ei + c);
                stage[p] = ((u64)uu[c] << 32) | (u64)(~idx);
            }
        }
    }
    __syncthreads();
    if (t == 0) lbase = atomicAdd(&cnt[b], lcount);
    __syncthreads();
    const int nb = lcount, gb = lbase;
    u64* kb = keys + (size_t)b * CAP;
    for (int i = t; i < nb; i += 256) {
        int gp = gb + i;
        if (gp < CAP) kb[gp] = stage[i];
    }
}

__device__ __forceinline__ float4 decode_box(u64 key, int b,
                                             const float4* __restrict__ anchors4,
                                             const float4* __restrict__ deltas4) {
    u32 idx = ~(u32)(key & 0xFFFFFFFFu);
    float4 a = anchors4[idx];                       // [xmin,xmax,ymin,ymax]
    float4 d = deltas4[(size_t)b * NPB + idx];      // [tx,ty,tw,th]
    float xa = (a.x + a.y) * 0.5f;
    float ya = (a.z + a.w) * 0.5f;
    float wa = a.y - a.x;
    float ha = a.w - a.z;
    float x = d.x * wa + xa;
    float y = d.y * ha + ya;
    float w = expf(d.z) * wa;
    float h = expf(d.w) * ha;
    float4 bx;
    bx.x = fminf(y + h * 0.5f, 1.f);   // ymax
    bx.y = fmaxf(x - w * 0.5f, 0.f);   // xmin
    bx.z = fmaxf(y - h * 0.5f, 0.f);   // ymin
    bx.w = fminf(x + w * 0.5f, 1.f);   // xmax
    return bx;
}

// Wave-level candidate-form greedy NMS, 2 candidates per iteration.
// Candidate j is picked iff IoU(j, p) <= T for all earlier picks p (equivalent
// to the reference argmax/suppress scan by induction). The j<->j+1 interaction
// is resolved with a lane-uniform IoU (no extra ballot). Picks live 2/lane.
__device__ __forceinline__ int wave_nms(const float4* __restrict__ boxes, int n,
                                        float4* __restrict__ out4, int lane) {
    float4 pb0 = make_float4(0.f, 0.f, 0.f, 0.f), pb1 = pb0;
    float pa0 = 0.f, pa1 = 0.f;
    int np = 0;
#define ACCEPT(cb, ar) do { \
        if (lane == (np & 63)) { \
            if (np < 64) { pb0 = cb; pa0 = ar; } else { pb1 = cb; pa1 = ar; } \
            out4[np] = cb; } \
        ++np; } while (0)
    for (int j = 0; j < n; j += 2) {
        const bool have1 = (j + 1 < n);
        float4 c0 = boxes[j];                       // LDS same-address broadcast
        float4 c1 = boxes[have1 ? j + 1 : j];
        float ar0 = fmaxf(c0.x - c0.z, 0.f) * fmaxf(c0.w - c0.y, 0.f);
        float ar1 = fmaxf(c1.x - c1.z, 0.f) * fmaxf(c1.w - c1.y, 0.f);
        bool s0 = false, s1 = false;
        if (lane < np) {
            float ih = fmaxf(fminf(pb0.x, c0.x) - fmaxf(pb0.z, c0.z), 0.f);
            float iw = fmaxf(fminf(pb0.w, c0.w) - fmaxf(pb0.y, c0.y), 0.f);
            float inter = ih * iw;
            s0 = inter / (pa0 + ar0 - inter + 1e-9f) > IOU_T;
            ih = fmaxf(fminf(pb0.x, c1.x) - fmaxf(pb0.z, c1.z), 0.f);
            iw = fmaxf(fminf(pb0.w, c1.w) - fmaxf(pb0.y, c1.y), 0.f);
            inter = ih * iw;
            s1 = inter / (pa0 + ar1 - inter + 1e-9f) > IOU_T;
        }
        if (lane + 64 < np) {
            float ih = fmaxf(fminf(pb1.x, c0.x) - fmaxf(pb1.z, c0.z), 0.f);
            float iw = fmaxf(fminf(pb1.w, c0.w) - fmaxf(pb1.y, c0.y), 0.f);
            float inter = ih * iw;
            s0 = s0 || (inter / (pa1 + ar0 - inter + 1e-9f) > IOU_T);
            ih = fmaxf(fminf(pb1.x, c1.x) - fmaxf(pb1.z, c1.z), 0.f);
            iw = fmaxf(fminf(pb1.w, c1.w) - fmaxf(pb1.y, c1.y), 0.f);
            inter = ih * iw;
            s1 = s1 || (inter / (pa1 + ar1 - inter + 1e-9f) > IOU_T);
        }
        bool acc0 = !__any(s0);
        bool acc1 = !__any(s1);
        if (acc0) {
            ACCEPT(c0, ar0);
            if (np == MOS) break;
            if (have1 && acc1) {
                float ih = fmaxf(fminf(c0.x, c1.x) - fmaxf(c0.z, c1.z), 0.f);
                float iw = fmaxf(fminf(c0.w, c1.w) - fmaxf(c0.y, c1.y), 0.f);
                float inter = ih * iw;
                if (!(inter / (ar0 + ar1 - inter + 1e-9f) > IOU_T)) {
                    ACCEPT(c1, ar1);
                    if (np == MOS) break;
                }
            }
        } else if (have1 && acc1) {
            ACCEPT(c1, ar1);
            if (np == MOS) break;
        }
    }
#undef ACCEPT
    return np;
}

// One block (256 thr) per batch. Fast path: refine a per-batch bound on
// d = ONE_BITS - score_bits shifted to spread the keys over ~128-255 bins,
// capturing the top >=FAST_K (<=FAST_CAP) keys — an exact prefix of the
// global descending order. Sort those, decode, wave-0 NMS. Fallback (never
// for this data): full 4096 sort + 2048 decode.
__global__ __launch_bounds__(256) void sort_nms_kernel(
        const float* __restrict__ deltas, const float* __restrict__ anchors,
        const int* __restrict__ cnt, const u32* __restrict__ bound,
        const u64* __restrict__ keys, float* __restrict__ out) {
    __shared__ __align__(16) u64 key_s[CAP];         // 32 KB
    __shared__ __align__(16) float4 boxes[PRE_NMS];  // 32 KB
    __shared__ u64 fast_k[FAST_CAP];                 // 4 KB
    __shared__ int lh[256];
    __shared__ int s_cnt, s_nsel, s_flag, s_cbin, s_sh;

    const int t = threadIdx.x;
    const int b = blockIdx.x;
    const int nc = min(cnt[b], CAP);
    const u64* kb = keys + (size_t)b * CAP;
    const float4* anchors4 = (const float4*)anchors;
    const float4* deltas4  = (const float4*)deltas;
    float4* out4 = (float4*)out + (size_t)b * MOS;

    lh[t] = 0;
    if (t == 0) {
        s_cnt = 0;
        u32 dmax = ONE_BITS - bound[b];        // bound <= 0x3F7F0000 < ONE_BITS
        int bits = 32 - __builtin_clz(dmax);   // dmax >= 1
        s_sh = (bits > 8) ? (bits - 8) : 0;
    }
    __syncthreads();
    const int sh = s_sh;

    // Load keys + histogram of distance bins (d >> sh), d = ONE_BITS - hi.
#pragma unroll
    for (int p = 0; p < CAP / 256; ++p) {
        int i = t + p * 256;
        u64 k = (i < nc) ? kb[i] : 0ULL;
        key_s[i] = k;
        if (i < nc) {
            u32 d = ONE_BITS - (u32)(k >> 32);
            u32 bin = d >> sh;
            if (bin > 255u) bin = 255u;
            atomicAdd(&lh[bin], 1);
        }
    }
    for (int i = t; i < FAST_CAP; i += 256) fast_k[i] = 0ULL;
    __syncthreads();

    // Scan bins from best (0) up: smallest prefix with count >= FAST_K.
    if (t == 0) {
        int cum = 0; bool hit = false;
        for (int v = 0; v < 256; ++v) {
            cum += lh[v];
            if (cum >= FAST_K) {
                if (cum > FAST_CAP) { s_nsel = cum - lh[v]; s_cbin = v - 1; }
                else                { s_nsel = cum;         s_cbin = v; }
                hit = true; break;
            }
        }
        if (!hit) { s_nsel = cum; s_cbin = 255; }   // nc < FAST_K: take all
    }
    __syncthreads();
    const int cbin = s_cbin;
    const int n_sel = s_nsel;

    // Compact the selected prefix set into fast_k (order fixed by the sort).
#pragma unroll
    for (int p = 0; p < CAP / 256; ++p) {
        int i = t + p * 256;
        if (i < nc) {
            u64 k = key_s[i];
            u32 d = ONE_BITS - (u32)(k >> 32);
            u32 bin = d >> sh;
            if (bin > 255u) bin = 255u;
            if ((int)bin <= cbin) fast_k[atomicAdd(&s_cnt, 1)] = k;
        }
    }
    __syncthreads();

    // Bitonic sort fast_k[512] desc (unique nonzero keys; pads sink to tail).
    for (int k = 2; k <= FAST_CAP; k <<= 1) {
        for (int j = k >> 1; j > 0; j >>= 1) {
            for (int i = t; i < FAST_CAP; i += 256) {
                int ix = i ^ j;
                if (ix > i) {
                    u64 a = fast_k[i], c = fast_k[ix];
                    bool up = ((i & k) == 0);
                    if (up ? (a < c) : (a > c)) { fast_k[i] = c; fast_k[ix] = a; }
                }
            }
            __syncthreads();
        }
    }

    // Decode fast prefix.
    for (int i = t; i < FAST_CAP; i += 256)
        boxes[i] = (i < n_sel) ? decode_box(fast_k[i], b, anchors4, deltas4)
                               : make_float4(0.f, 0.f, 0.f, 0.f);
    __syncthreads();

    if (t < 64) {
        int np = wave_nms(boxes, n_sel, out4, t);
        bool success = (np == MOS) || (n_sel == nc);
        if (success)
            for (int i = np + t; i < MOS; i += 64)
                out4[i] = make_float4(0.f, 0.f, 0.f, 0.f);
        if (t == 0) s_flag = success ? 1 : 0;
    }
    __syncthreads();
    if (s_flag) return;

    // ---------- Fallback: exact full path (rare by data, required by rigor) --
    for (int k = 2; k <= CAP; k <<= 1) {
        for (int j = k >> 1; j > 0; j >>= 1) {
            for (int i = t; i < CAP; i += 256) {
                int ix = i ^ j;
                if (ix > i) {
                    u64 a = key_s[i], c = key_s[ix];
                    bool up = ((i & k) == 0);
                    if (up ? (a < c) : (a > c)) { key_s[i] = c; key_s[ix] = a; }
                }
            }
            __syncthreads();
        }
    }
    const int nvalid = min(nc, PRE_NMS);
    for (int i = t; i < PRE_NMS; i += 256)
        boxes[i] = (i < nvalid) ? decode_box(key_s[i], b, anchors4, deltas4)
                                : make_float4(0.f, 0.f, 0.f, 0.f);
    __syncthreads();
    if (t < 64) {
        int np = wave_nms(boxes, nvalid, out4, t);
        for (int i = np + t; i < MOS; i += 64)
            out4[i] = make_float4(0.f, 0.f, 0.f, 0.f);
    }
}

extern "C" void kernel_launch(void* const* d_in, const int* in_sizes, int n_in,
                              void* d_out, int out_size, void* d_ws, size_t ws_size,
                              hipStream_t stream) {
    const float* score_map = (const float*)d_in[0];
    const float* delta_map = (const float*)d_in[1];
    const float* anchors   = (const float*)d_in[2];
    float* out = (float*)d_out;
    const int B = in_sizes[0] / NPB;   // 32

    char* ws = (char*)d_ws;
    size_t off = 0;
    int* hist  = (int*)(ws + off); off += (size_t)B * 256 * 4;
    int* cnt   = (int*)(ws + off); off += (size_t)B * 4;
    u32* bound = (u32*)(ws + off); off += (size_t)B * 4;
    int* flag  = (int*)(ws + off); off += (size_t)B * 4;
    u64* keys  = (u64*)(ws + off);

    const int meta_n = B * 256 + B;   // hist + cnt (contiguous)
    zero_meta<<<(meta_n + 255) / 256, 256, 0, stream>>>(hist, meta_n);
    spec_compact_kernel<<<dim3(NPB / 4096, B), 256, 0, stream>>>(
        (const uint4*)score_map, hist, cnt, keys);
    fixup_kernel<<<1, 64, 0, stream>>>(hist, cnt, bound, flag, B);
    repair_compact_kernel<<<dim3(NPB / 4096, B), 256, 0, stream>>>(
        (const uint4*)score_map, bound, flag, cnt, keys);
    sort_nms_kernel<<<B, 256, 0, stream>>>(delta_map, anchors, cnt, bound, keys, out);
}

// Round 6
// 297.647 us; speedup vs baseline: 1.6655x; 1.0113x over previous
//
#include <hip/hip_runtime.h>
#include <stdint.h>

#pragma clang fp contract(off)

typedef unsigned long long u64;
typedef unsigned int u32;

#define NH 192
#define NW 192
#define NK 9
#define NPB (NH * NW * NK)   // 331776 anchors per batch
#define PRE_NMS 2048
#define CAP 4096             // candidate capacity per batch
#define FAST_CAP 512         // fast-path sorted-prefix capacity
#define FAST_K 256           // fast-path target prefix size
#define MOS 100
#define SCORE_T_BITS 0x3F666666u   // float bits of 0.9f (scores in [0,1) -> positive)
#define SPEC_BITS   0x3F7E0000u    // speculative bound: score >= 0.9921875
                                   // E[cnt]=2592/batch, sigma~51 -> in [2048,4096] w/ >10 sigma
#define ONE_BITS 0x3F800000u       // float bits of 1.0f
#define IOU_T 0.9f

// ws layout: cnt B int | keys B*CAP u64

__global__ void zero_cnt(int* __restrict__ cnt, int n) {
    int i = threadIdx.x;
    if (i < n) cnt[i] = 0;
}

// ONE lean pass over scores: compact bits >= SPEC_BITS into keys
// (score_bits<<32)|~idx. grid (81,B), block 256, 16 scores/thread.
__global__ void spec_compact_kernel(const uint4* __restrict__ scores,
                                    int* __restrict__ cnt,
                                    u64* __restrict__ keys) {
    __shared__ u64 stage[512];
    __shared__ int lcount, lbase;
    const int t = threadIdx.x;
    if (t == 0) lcount = 0;
    __syncthreads();
    const int b = blockIdx.y;
    const int base_i = blockIdx.x * 4096;
    const uint4* sp = scores + (size_t)b * (NPB / 4) + (size_t)blockIdx.x * 1024;
#pragma unroll
    for (int i = 0; i < 4; ++i) {
        uint4 v = sp[t + i * 256];
        int ei = base_i + (t + i * 256) * 4;
        u32 uu[4] = {v.x, v.y, v.z, v.w};
#pragma unroll
        for (int c = 0; c < 4; ++c) {
            u32 u = uu[c];
            if (u >= SPEC_BITS) {
                int p = atomicAdd(&lcount, 1);
                u32 idx = (u32)(ei + c);
                if (p < 512) stage[p] = ((u64)u << 32) | (u64)(~idx);
            }
        }
    }
    __syncthreads();
    if (t == 0) lbase = atomicAdd(&cnt[b], lcount);
    __syncthreads();
    const int nb = min(lcount, 512), gb = lbase;   // >512/block impossible (40 sigma);
    u64* kb = keys + (size_t)b * CAP;              // if it happened, cnt>CAP -> repair
    for (int i = t; i < nb; i += 256) {
        int gp = gb + i;
        if (gp < CAP) kb[gp] = stage[i];
    }
}

__device__ __forceinline__ float4 decode_box(u64 key, int b,
                                             const float4* __restrict__ anchors4,
                                             const float4* __restrict__ deltas4) {
    u32 idx = ~(u32)(key & 0xFFFFFFFFu);
    float4 a = anchors4[idx];                       // [xmin,xmax,ymin,ymax]
    float4 d = deltas4[(size_t)b * NPB + idx];      // [tx,ty,tw,th]
    float xa = (a.x + a.y) * 0.5f;
    float ya = (a.z + a.w) * 0.5f;
    float wa = a.y - a.x;
    float ha = a.w - a.z;
    float x = d.x * wa + xa;
    float y = d.y * ha + ya;
    float w = expf(d.z) * wa;
    float h = expf(d.w) * ha;
    float4 bx;
    bx.x = fminf(y + h * 0.5f, 1.f);   // ymax
    bx.y = fmaxf(x - w * 0.5f, 0.f);   // xmin
    bx.z = fmaxf(y - h * 0.5f, 0.f);   // ymin
    bx.w = fminf(x + w * 0.5f, 1.f);   // xmax
    return bx;
}

// Wave-level candidate-form greedy NMS, 2 candidates/iter with next-pair
// register prefetch. Candidate j is picked iff IoU(j,p) <= T for all earlier
// picks p (equivalent to the reference argmax/suppress scan by induction).
// The j<->j+1 interaction is resolved lane-uniformly. Picks live 2/lane.
__device__ __forceinline__ int wave_nms(const float4* __restrict__ boxes, int n,
                                        float4* __restrict__ out4, int lane) {
    float4 pb0 = make_float4(0.f, 0.f, 0.f, 0.f), pb1 = pb0;
    float pa0 = 0.f, pa1 = 0.f;
    int np = 0;
    if (n <= 0) return 0;
#define ACCEPT(cb, ar) do { \
        if (lane == (np & 63)) { \
            if (np < 64) { pb0 = cb; pa0 = ar; } else { pb1 = cb; pa1 = ar; } \
            out4[np] = cb; } \
        ++np; } while (0)
    float4 n0 = boxes[0];
    float4 n1 = boxes[(1 < n) ? 1 : 0];
    for (int j = 0; j < n; j += 2) {
        const bool have1 = (j + 1 < n);
        float4 c0 = n0, c1 = n1;
        int jn0 = (j + 2 < n) ? j + 2 : j;
        int jn1 = (j + 3 < n) ? j + 3 : jn0;
        n0 = boxes[jn0];               // prefetch next pair (LDS broadcast)
        n1 = boxes[jn1];
        float ar0 = fmaxf(c0.x - c0.z, 0.f) * fmaxf(c0.w - c0.y, 0.f);
        float ar1 = fmaxf(c1.x - c1.z, 0.f) * fmaxf(c1.w - c1.y, 0.f);
        bool s0 = false, s1 = false;
        if (lane < np) {
            float ih = fmaxf(fminf(pb0.x, c0.x) - fmaxf(pb0.z, c0.z), 0.f);
            float iw = fmaxf(fminf(pb0.w, c0.w) - fmaxf(pb0.y, c0.y), 0.f);
            float inter = ih * iw;
            s0 = inter / (pa0 + ar0 - inter + 1e-9f) > IOU_T;
            ih = fmaxf(fminf(pb0.x, c1.x) - fmaxf(pb0.z, c1.z), 0.f);
            iw = fmaxf(fminf(pb0.w, c1.w) - fmaxf(pb0.y, c1.y), 0.f);
            inter = ih * iw;
            s1 = inter / (pa0 + ar1 - inter + 1e-9f) > IOU_T;
        }
        if (lane + 64 < np) {
            float ih = fmaxf(fminf(pb1.x, c0.x) - fmaxf(pb1.z, c0.z), 0.f);
            float iw = fmaxf(fminf(pb1.w, c0.w) - fmaxf(pb1.y, c0.y), 0.f);
            float inter = ih * iw;
            s0 = s0 || (inter / (pa1 + ar0 - inter + 1e-9f) > IOU_T);
            ih = fmaxf(fminf(pb1.x, c1.x) - fmaxf(pb1.z, c1.z), 0.f);
            iw = fmaxf(fminf(pb1.w, c1.w) - fmaxf(pb1.y, c1.y), 0.f);
            inter = ih * iw;
            s1 = s1 || (inter / (pa1 + ar1 - inter + 1e-9f) > IOU_T);
        }
        bool acc0 = !__any(s0);
        bool acc1 = !__any(s1);
        if (acc0) {
            ACCEPT(c0, ar0);
            if (np == MOS) break;
            if (have1 && acc1) {
                float ih = fmaxf(fminf(c0.x, c1.x) - fmaxf(c0.z, c1.z), 0.f);
                float iw = fmaxf(fminf(c0.w, c1.w) - fmaxf(c0.y, c1.y), 0.f);
                float inter = ih * iw;
                if (!(inter / (ar0 + ar1 - inter + 1e-9f) > IOU_T)) {
                    ACCEPT(c1, ar1);
                    if (np == MOS) break;
                }
            }
        } else if (have1 && acc1) {
            ACCEPT(c1, ar1);
            if (np == MOS) break;
        }
    }
#undef ACCEPT
    return np;
}

// One block (256 thr) per batch. Validates the speculative candidate set
// (cnt in [PRE_NMS, CAP] -> superset of exact top-2048); on miss (never for
// this data, >10 sigma) repairs in-kernel via a 3-pass re-read of this
// batch's scores with two-level bound refinement (round-4 thresh semantics,
// refined to (bits>>8) granularity). Then: refine a distance-bin bound
// capturing the top >=FAST_K (<=FAST_CAP) keys — an exact prefix of the
// global descending order — sort those, decode, wave-0 NMS. Full-sort
// fallback if the prefix is exhausted early.
__global__ __launch_bounds__(256) void sort_nms_kernel(
        const uint4* __restrict__ scores,
        const float* __restrict__ deltas, const float* __restrict__ anchors,
        const int* __restrict__ cnt, const u64* __restrict__ keys,
        float* __restrict__ out) {
    __shared__ __align__(16) u64 key_s[CAP];         // 32 KB
    __shared__ __align__(16) float4 boxes[PRE_NMS];  // 32 KB
    __shared__ u64 fast_k[FAST_CAP];                 // 4 KB
    __shared__ int lh[256];
    __shared__ int s_cnt, s_nsel, s_flag, s_cbin, s_sh, s_nc;
    __shared__ u32 s_bd;
    __shared__ int s_tv, s_cumabove, s_skipB;

    const int t = threadIdx.x;
    const int b = blockIdx.x;
    const float4* anchors4 = (const float4*)anchors;
    const float4* deltas4  = (const float4*)deltas;
    float4* out4 = (float4*)out + (size_t)b * MOS;

    const int nc0 = cnt[b];
    const bool valid = (nc0 >= PRE_NMS && nc0 <= CAP);

    if (valid) {
        const u64* kb = keys + (size_t)b * CAP;
#pragma unroll
        for (int p = 0; p < CAP / 256; ++p) {
            int i = t + p * 256;
            key_s[i] = (i < nc0) ? kb[i] : 0ULL;
        }
        if (t == 0) { s_nc = nc0; s_bd = SPEC_BITS; }
        __syncthreads();
    } else {
        // ---- In-kernel repair (never taken for this data) ----
        const uint4* sp = scores + (size_t)b * (NPB / 4);
        // Pass A: hist of (bits>>16)&0xFF for bits > SCORE_T.
        lh[t] = 0;
        __syncthreads();
        for (int i = t; i < NPB / 4; i += 256) {
            uint4 v = sp[i];
            u32 uu[4] = {v.x, v.y, v.z, v.w};
#pragma unroll
            for (int c = 0; c < 4; ++c)
                if (uu[c] > SCORE_T_BITS) atomicAdd(&lh[(uu[c] >> 16) & 0xFF], 1);
        }
        __syncthreads();
        if (t == 0) {
            int cum = 0, tv = -1, cumab = 0;
            for (int v = 255; v >= 0; --v) {
                int h = lh[v];
                if (cum + h >= PRE_NMS) { tv = v; cumab = cum; break; }
                cum += h;
            }
            if (tv < 0) { s_bd = SCORE_T_BITS + 1; s_skipB = 1; }  // <2048 total: take all
            else        { s_tv = tv; s_cumabove = cumab; s_skipB = 0; }
        }
        __syncthreads();
        if (!s_skipB) {
            // Pass B: refine within crossing bucket at (bits>>8) granularity.
            const int tv = s_tv;
            lh[t] = 0;
            __syncthreads();
            for (int i = t; i < NPB / 4; i += 256) {
                uint4 v = sp[i];
                u32 uu[4] = {v.x, v.y, v.z, v.w};
#pragma unroll
                for (int c = 0; c < 4; ++c)
                    if (uu[c] > SCORE_T_BITS && (int)((uu[c] >> 16) & 0xFF) == tv)
                        atomicAdd(&lh[(uu[c] >> 8) & 0xFF], 1);
            }
            __syncthreads();
            if (t == 0) {
                int cum = s_cumabove, iv = 0;
                for (int v = 255; v >= 0; --v) {
                    cum += lh[v];
                    if (cum >= PRE_NMS) {
                        // if window overflows CAP, step one finer bin up
                        iv = (cum > CAP && v < 255) ? v + 1 : v;
                        break;
                    }
                }
                u32 bd = (((u32)(0x3F00 + tv)) << 16) | ((u32)iv << 8);
                if (bd < SCORE_T_BITS + 1) bd = SCORE_T_BITS + 1;
                s_bd = bd;
            }
        }
        __syncthreads();
        // Pass C: compact bits >= s_bd into key_s.
        if (t == 0) s_cnt = 0;
        __syncthreads();
        const u32 bd = s_bd;
        for (int i = t; i < NPB / 4; i += 256) {
            uint4 v = sp[i];
            u32 uu[4] = {v.x, v.y, v.z, v.w};
#pragma unroll
            for (int c = 0; c < 4; ++c) {
                if (uu[c] >= bd) {
                    int p = atomicAdd(&s_cnt, 1);
                    u32 idx = (u32)(i * 4 + c);
                    if (p < CAP) key_s[p] = ((u64)uu[c] << 32) | (u64)(~idx);
                }
            }
        }
        __syncthreads();
        if (t == 0) s_nc = min(s_cnt, CAP);
        __syncthreads();
        for (int p = 0; p < CAP / 256; ++p) {
            int i = t + p * 256;
            if (i >= s_nc) key_s[i] = 0ULL;
        }
        __syncthreads();
    }

    const int nc = s_nc;
    // sh spreads d = ONE_BITS - score_bits over ~128-255 bins.
    if (t == 0) {
        s_cnt = 0;
        u32 dmax = ONE_BITS - s_bd;
        int bits = 32 - __builtin_clz(dmax);
        s_sh = (bits > 8) ? (bits - 8) : 0;
    }
    lh[t] = 0;
    __syncthreads();
    const int sh = s_sh;

    // Histogram of distance bins over key_s.
#pragma unroll
    for (int p = 0; p < CAP / 256; ++p) {
        int i = t + p * 256;
        if (i < nc) {
            u32 d = ONE_BITS - (u32)(key_s[i] >> 32);
            u32 bin = d >> sh;
            if (bin > 255u) bin = 255u;
            atomicAdd(&lh[bin], 1);
        }
    }
    for (int i = t; i < FAST_CAP; i += 256) fast_k[i] = 0ULL;
    __syncthreads();

    // Smallest bin-prefix with count >= FAST_K (<= FAST_CAP).
    if (t == 0) {
        int cum = 0; bool hit = false;
        for (int v = 0; v < 256; ++v) {
            cum += lh[v];
            if (cum >= FAST_K) {
                if (cum > FAST_CAP) { s_nsel = cum - lh[v]; s_cbin = v - 1; }
                else                { s_nsel = cum;         s_cbin = v; }
                hit = true; break;
            }
        }
        if (!hit) { s_nsel = cum; s_cbin = 255; }   // nc < FAST_K: take all
    }
    __syncthreads();
    const int cbin = s_cbin;
    const int n_sel = s_nsel;

    // Compact the selected prefix set into fast_k (order fixed by the sort).
#pragma unroll
    for (int p = 0; p < CAP / 256; ++p) {
        int i = t + p * 256;
        if (i < nc) {
            u64 k = key_s[i];
            u32 d = ONE_BITS - (u32)(k >> 32);
            u32 bin = d >> sh;
            if (bin > 255u) bin = 255u;
            if ((int)bin <= cbin) fast_k[atomicAdd(&s_cnt, 1)] = k;
        }
    }
    __syncthreads();

    // Bitonic sort fast_k[512] desc (unique nonzero keys; pads sink to tail).
    for (int k = 2; k <= FAST_CAP; k <<= 1) {
        for (int j = k >> 1; j > 0; j >>= 1) {
            for (int i = t; i < FAST_CAP; i += 256) {
                int ix = i ^ j;
                if (ix > i) {
                    u64 a = fast_k[i], c = fast_k[ix];
                    bool up = ((i & k) == 0);
                    if (up ? (a < c) : (a > c)) { fast_k[i] = c; fast_k[ix] = a; }
                }
            }
            __syncthreads();
        }
    }

    // Decode fast prefix.
    for (int i = t; i < FAST_CAP; i += 256)
        boxes[i] = (i < n_sel) ? decode_box(fast_k[i], b, anchors4, deltas4)
                               : make_float4(0.f, 0.f, 0.f, 0.f);
    __syncthreads();

    if (t < 64) {
        int np = wave_nms(boxes, n_sel, out4, t);
        bool success = (np == MOS) || (n_sel == nc);
        if (success)
            for (int i = np + t; i < MOS; i += 64)
                out4[i] = make_float4(0.f, 0.f, 0.f, 0.f);
        if (t == 0) s_flag = success ? 1 : 0;
    }
    __syncthreads();
    if (s_flag) return;

    // ---------- Fallback: full sort of all candidates (rare by data) --------
    for (int k = 2; k <= CAP; k <<= 1) {
        for (int j = k >> 1; j > 0; j >>= 1) {
            for (int i = t; i < CAP; i += 256) {
                int ix = i ^ j;
                if (ix > i) {
                    u64 a = key_s[i], c = key_s[ix];
                    bool up = ((i & k) == 0);
                    if (up ? (a < c) : (a > c)) { key_s[i] = c; key_s[ix] = a; }
                }
            }
            __syncthreads();
        }
    }
    const int nvalid = min(nc, PRE_NMS);
    for (int i = t; i < PRE_NMS; i += 256)
        boxes[i] = (i < nvalid) ? decode_box(key_s[i], b, anchors4, deltas4)
                                : make_float4(0.f, 0.f, 0.f, 0.f);
    __syncthreads();
    if (t < 64) {
        int np = wave_nms(boxes, nvalid, out4, t);
        for (int i = np + t; i < MOS; i += 64)
            out4[i] = make_float4(0.f, 0.f, 0.f, 0.f);
    }
}

extern "C" void kernel_launch(void* const* d_in, const int* in_sizes, int n_in,
                              void* d_out, int out_size, void* d_ws, size_t ws_size,
                              hipStream_t stream) {
    const float* score_map = (const float*)d_in[0];
    const float* delta_map = (const float*)d_in[1];
    const float* anchors   = (const float*)d_in[2];
    float* out = (float*)d_out;
    const int B = in_sizes[0] / NPB;   // 32

    char* ws = (char*)d_ws;
    int* cnt  = (int*)ws;                       // B ints
    u64* keys = (u64*)(ws + (size_t)B * 4 + 4); // align pad; B*CAP u64
    keys = (u64*)(((uintptr_t)keys + 15) & ~(uintptr_t)15);

    zero_cnt<<<1, 64, 0, stream>>>(cnt, B);
    spec_compact_kernel<<<dim3(NPB / 4096, B), 256, 0, stream>>>(
        (const uint4*)score_map, cnt, keys);
    sort_nms_kernel<<<B, 256, 0, stream>>>(
        (const uint4*)score_map, delta_map, anchors, cnt, keys, out);
}

// Round 7
// 277.332 us; speedup vs baseline: 1.7875x; 1.0733x over previous
//
#include <hip/hip_runtime.h>
#include <stdint.h>

#pragma clang fp contract(off)

typedef unsigned long long u64;
typedef unsigned int u32;

#define NH 192
#define NW 192
#define NK 9
#define NPB (NH * NW * NK)   // 331776 anchors per batch
#define NSLOT 81             // score-pass blocks per batch
#define SLOT 96              // key slots per block (mean 32, sigma 5.6 -> 11 sigma)
#define PRE_NMS 2048
#define CAP 4096             // candidate capacity per batch
#define FAST_CAP 512         // fast-path sorted-prefix capacity
#define FAST_K 256           // fast-path target prefix size
#define MOS 100
#define SCORE_T_BITS 0x3F666666u   // float bits of 0.9f (scores in [0,1) -> positive)
#define SPEC_BITS   0x3F7E0000u    // speculative bound: score >= 0.9921875
                                   // E[total]=2592/batch, sigma~51 -> in [2048,4096] w/ >10 sigma
#define ONE_BITS 0x3F800000u       // float bits of 1.0f
#define IOU_T 0.9f

// ws layout: bcnt B*NSLOT int | (16B align) keys B*NSLOT*SLOT u64

// ONE lean pass over scores: compact bits >= SPEC_BITS into per-block slots.
// No zero-init needed (counts written unconditionally), no global atomics.
// grid (81,B), block 256, 16 scores/thread.
__global__ void spec_compact_kernel(const uint4* __restrict__ scores,
                                    int* __restrict__ bcnt,
                                    u64* __restrict__ keys) {
    __shared__ u64 stage[SLOT];
    __shared__ int lcount;
    const int t = threadIdx.x;
    if (t == 0) lcount = 0;
    __syncthreads();
    const int b = blockIdx.y, blk = blockIdx.x;
    const int base_i = blk * 4096;
    const uint4* sp = scores + (size_t)b * (NPB / 4) + (size_t)blk * 1024;
#pragma unroll
    for (int i = 0; i < 4; ++i) {
        uint4 v = sp[t + i * 256];
        int ei = base_i + (t + i * 256) * 4;
        u32 uu[4] = {v.x, v.y, v.z, v.w};
#pragma unroll
        for (int c = 0; c < 4; ++c) {
            u32 u = uu[c];
            if (u >= SPEC_BITS) {
                int p = atomicAdd(&lcount, 1);
                u32 idx = (u32)(ei + c);
                if (p < SLOT) stage[p] = ((u64)u << 32) | (u64)(~idx);
            }
        }
    }
    __syncthreads();
    const int n = lcount;
    if (t == 0) bcnt[b * NSLOT + blk] = n;   // >SLOT -> sort_nms repairs this batch
    u64* kb = keys + ((size_t)b * NSLOT + blk) * SLOT;
    const int nw = min(n, SLOT);
    for (int i = t; i < nw; i += 256) kb[i] = stage[i];
}

__device__ __forceinline__ float4 decode_box(u64 key, int b,
                                             const float4* __restrict__ anchors4,
                                             const float4* __restrict__ deltas4) {
    u32 idx = ~(u32)(key & 0xFFFFFFFFu);
    float4 a = anchors4[idx];                       // [xmin,xmax,ymin,ymax]
    float4 d = deltas4[(size_t)b * NPB + idx];      // [tx,ty,tw,th]
    float xa = (a.x + a.y) * 0.5f;
    float ya = (a.z + a.w) * 0.5f;
    float wa = a.y - a.x;
    float ha = a.w - a.z;
    float x = d.x * wa + xa;
    float y = d.y * ha + ya;
    float w = expf(d.z) * wa;
    float h = expf(d.w) * ha;
    float4 bx;
    bx.x = fminf(y + h * 0.5f, 1.f);   // ymax
    bx.y = fmaxf(x - w * 0.5f, 0.f);   // xmin
    bx.z = fmaxf(y - h * 0.5f, 0.f);   // ymin
    bx.w = fminf(x + w * 0.5f, 1.f);   // xmax
    return bx;
}

// Wave-level candidate-form greedy NMS, 2 candidates/iter with next-pair
// register prefetch. Candidate j is picked iff IoU(j,p) <= T for all earlier
// picks p (equivalent to the reference argmax/suppress scan by induction).
// The j<->j+1 interaction is resolved lane-uniformly. Picks live 2/lane.
__device__ __forceinline__ int wave_nms(const float4* __restrict__ boxes, int n,
                                        float4* __restrict__ out4, int lane) {
    float4 pb0 = make_float4(0.f, 0.f, 0.f, 0.f), pb1 = pb0;
    float pa0 = 0.f, pa1 = 0.f;
    int np = 0;
    if (n <= 0) return 0;
#define ACCEPT(cb, ar) do { \
        if (lane == (np & 63)) { \
            if (np < 64) { pb0 = cb; pa0 = ar; } else { pb1 = cb; pa1 = ar; } \
            out4[np] = cb; } \
        ++np; } while (0)
    float4 n0 = boxes[0];
    float4 n1 = boxes[(1 < n) ? 1 : 0];
    for (int j = 0; j < n; j += 2) {
        const bool have1 = (j + 1 < n);
        float4 c0 = n0, c1 = n1;
        int jn0 = (j + 2 < n) ? j + 2 : j;
        int jn1 = (j + 3 < n) ? j + 3 : jn0;
        n0 = boxes[jn0];               // prefetch next pair (LDS broadcast)
        n1 = boxes[jn1];
        float ar0 = fmaxf(c0.x - c0.z, 0.f) * fmaxf(c0.w - c0.y, 0.f);
        float ar1 = fmaxf(c1.x - c1.z, 0.f) * fmaxf(c1.w - c1.y, 0.f);
        bool s0 = false, s1 = false;
        if (lane < np) {
            float ih = fmaxf(fminf(pb0.x, c0.x) - fmaxf(pb0.z, c0.z), 0.f);
            float iw = fmaxf(fminf(pb0.w, c0.w) - fmaxf(pb0.y, c0.y), 0.f);
            float inter = ih * iw;
            s0 = inter / (pa0 + ar0 - inter + 1e-9f) > IOU_T;
            ih = fmaxf(fminf(pb0.x, c1.x) - fmaxf(pb0.z, c1.z), 0.f);
            iw = fmaxf(fminf(pb0.w, c1.w) - fmaxf(pb0.y, c1.y), 0.f);
            inter = ih * iw;
            s1 = inter / (pa0 + ar1 - inter + 1e-9f) > IOU_T;
        }
        if (lane + 64 < np) {
            float ih = fmaxf(fminf(pb1.x, c0.x) - fmaxf(pb1.z, c0.z), 0.f);
            float iw = fmaxf(fminf(pb1.w, c0.w) - fmaxf(pb1.y, c0.y), 0.f);
            float inter = ih * iw;
            s0 = s0 || (inter / (pa1 + ar0 - inter + 1e-9f) > IOU_T);
            ih = fmaxf(fminf(pb1.x, c1.x) - fmaxf(pb1.z, c1.z), 0.f);
            iw = fmaxf(fminf(pb1.w, c1.w) - fmaxf(pb1.y, c1.y), 0.f);
            inter = ih * iw;
            s1 = s1 || (inter / (pa1 + ar1 - inter + 1e-9f) > IOU_T);
        }
        bool acc0 = !__any(s0);
        bool acc1 = !__any(s1);
        if (acc0) {
            ACCEPT(c0, ar0);
            if (np == MOS) break;
            if (have1 && acc1) {
                float ih = fmaxf(fminf(c0.x, c1.x) - fmaxf(c0.z, c1.z), 0.f);
                float iw = fmaxf(fminf(c0.w, c1.w) - fmaxf(c0.y, c1.y), 0.f);
                float inter = ih * iw;
                if (!(inter / (ar0 + ar1 - inter + 1e-9f) > IOU_T)) {
                    ACCEPT(c1, ar1);
                    if (np == MOS) break;
                }
            }
        } else if (have1 && acc1) {
            ACCEPT(c1, ar1);
            if (np == MOS) break;
        }
    }
#undef ACCEPT
    return np;
}

// One block (256 thr) per batch. Validates the per-slot speculative candidate
// set (total in [PRE_NMS,CAP], every slot count <= SLOT -> superset of exact
// top-2048); on miss (never for this data, >10 sigma) repairs in-kernel via a
// 3-pass re-read with two-level bound refinement. Then: distance-bin bound
// capturing the top >=FAST_K (<=FAST_CAP) keys — an exact prefix of the global
// descending order — RANK-order them (O(n^2) LDS-broadcast, 1 barrier; ranks
// are a permutation since keys are unique), decode into boxes[rank], wave-0
// NMS. Full-sort fallback if the prefix is exhausted early.
__global__ __launch_bounds__(256) void sort_nms_kernel(
        const uint4* __restrict__ scores,
        const float* __restrict__ deltas, const float* __restrict__ anchors,
        const int* __restrict__ bcnt, const u64* __restrict__ keys,
        float* __restrict__ out) {
    __shared__ __align__(16) u64 key_s[CAP];         // 32 KB
    __shared__ __align__(16) float4 boxes[PRE_NMS];  // 32 KB
    __shared__ u64 fast_k[FAST_CAP];                 // 4 KB
    __shared__ int lh[256];
    __shared__ int scnt_s[NSLOT];
    __shared__ int s_cnt, s_nsel, s_flag, s_cbin, s_sh, s_nc, s_ok;
    __shared__ u32 s_bd;
    __shared__ int s_tv, s_cumabove, s_skipB;

    const int t = threadIdx.x;
    const int b = blockIdx.x;
    const float4* anchors4 = (const float4*)anchors;
    const float4* deltas4  = (const float4*)deltas;
    float4* out4 = (float4*)out + (size_t)b * MOS;

    if (t < NSLOT) scnt_s[t] = bcnt[b * NSLOT + t];
    __syncthreads();
    if (t == 0) {
        int total = 0, maxc = 0;
        for (int s = 0; s < NSLOT; ++s) {
            int c = scnt_s[s];
            total += c;
            maxc = max(maxc, c);
        }
        s_nc = total;
        s_ok = (total >= PRE_NMS && total <= CAP && maxc <= SLOT) ? 1 : 0;
        s_cnt = 0;
        s_bd = SPEC_BITS;
    }
    __syncthreads();

    if (s_ok) {
        // Zero pad region, then gather all slots into key_s (order arbitrary —
        // ranking/sorting fixes it; keys are unique).
#pragma unroll
        for (int p = 0; p < CAP / 256; ++p) key_s[t + p * 256] = 0ULL;
        __syncthreads();
        const u64* kb = keys + (size_t)b * NSLOT * SLOT;
        for (int i = t; i < NSLOT * SLOT; i += 256) {
            int s = i / SLOT, j = i - s * SLOT;
            if (j < scnt_s[s])
                key_s[atomicAdd(&s_cnt, 1)] = kb[(size_t)s * SLOT + j];
        }
        __syncthreads();
    } else {
        // ---- In-kernel repair (never taken for this data) ----
        const uint4* sp = scores + (size_t)b * (NPB / 4);
        // Pass A: hist of (bits>>16)&0xFF for bits > SCORE_T.
        lh[t] = 0;
        __syncthreads();
        for (int i = t; i < NPB / 4; i += 256) {
            uint4 v = sp[i];
            u32 uu[4] = {v.x, v.y, v.z, v.w};
#pragma unroll
            for (int c = 0; c < 4; ++c)
                if (uu[c] > SCORE_T_BITS) atomicAdd(&lh[(uu[c] >> 16) & 0xFF], 1);
        }
        __syncthreads();
        if (t == 0) {
            int cum = 0, tv = -1, cumab = 0;
            for (int v = 255; v >= 0; --v) {
                int h = lh[v];
                if (cum + h >= PRE_NMS) { tv = v; cumab = cum; break; }
                cum += h;
            }
            if (tv < 0) { s_bd = SCORE_T_BITS + 1; s_skipB = 1; }  // <2048 total: take all
            else        { s_tv = tv; s_cumabove = cumab; s_skipB = 0; }
        }
        __syncthreads();
        if (!s_skipB) {
            // Pass B: refine within crossing bucket at (bits>>8) granularity.
            const int tv = s_tv;
            lh[t] = 0;
            __syncthreads();
            for (int i = t; i < NPB / 4; i += 256) {
                uint4 v = sp[i];
                u32 uu[4] = {v.x, v.y, v.z, v.w};
#pragma unroll
                for (int c = 0; c < 4; ++c)
                    if (uu[c] > SCORE_T_BITS && (int)((uu[c] >> 16) & 0xFF) == tv)
                        atomicAdd(&lh[(uu[c] >> 8) & 0xFF], 1);
            }
            __syncthreads();
            if (t == 0) {
                int cum = s_cumabove, iv = 0;
                for (int v = 255; v >= 0; --v) {
                    cum += lh[v];
                    if (cum >= PRE_NMS) {
                        iv = (cum > CAP && v < 255) ? v + 1 : v;
                        break;
                    }
                }
                u32 bd = (((u32)(0x3F00 + tv)) << 16) | ((u32)iv << 8);
                if (bd < SCORE_T_BITS + 1) bd = SCORE_T_BITS + 1;
                s_bd = bd;
            }
        }
        __syncthreads();
        // Pass C: compact bits >= s_bd into key_s.
        if (t == 0) s_cnt = 0;
        __syncthreads();
        const u32 bd = s_bd;
        for (int i = t; i < NPB / 4; i += 256) {
            uint4 v = sp[i];
            u32 uu[4] = {v.x, v.y, v.z, v.w};
#pragma unroll
            for (int c = 0; c < 4; ++c) {
                if (uu[c] >= bd) {
                    int p = atomicAdd(&s_cnt, 1);
                    u32 idx = (u32)(i * 4 + c);
                    if (p < CAP) key_s[p] = ((u64)uu[c] << 32) | (u64)(~idx);
                }
            }
        }
        __syncthreads();
        if (t == 0) s_nc = min(s_cnt, CAP);
        __syncthreads();
        for (int p = 0; p < CAP / 256; ++p) {
            int i = t + p * 256;
            if (i >= s_nc) key_s[i] = 0ULL;
        }
        __syncthreads();
    }

    const int nc = s_nc;
    // sh spreads d = ONE_BITS - score_bits over ~128-255 bins.
    if (t == 0) {
        s_cnt = 0;
        u32 dmax = ONE_BITS - s_bd;
        int bits = 32 - __builtin_clz(dmax);
        s_sh = (bits > 8) ? (bits - 8) : 0;
    }
    lh[t] = 0;
    __syncthreads();
    const int sh = s_sh;

    // Histogram of distance bins over key_s.
#pragma unroll
    for (int p = 0; p < CAP / 256; ++p) {
        int i = t + p * 256;
        if (i < nc) {
            u32 d = ONE_BITS - (u32)(key_s[i] >> 32);
            u32 bin = d >> sh;
            if (bin > 255u) bin = 255u;
            atomicAdd(&lh[bin], 1);
        }
    }
    for (int i = t; i < FAST_CAP; i += 256) fast_k[i] = 0ULL;
    __syncthreads();

    // Smallest bin-prefix with count >= FAST_K (<= FAST_CAP).
    if (t == 0) {
        int cum = 0; bool hit = false;
        for (int v = 0; v < 256; ++v) {
            cum += lh[v];
            if (cum >= FAST_K) {
                if (cum > FAST_CAP) { s_nsel = cum - lh[v]; s_cbin = v - 1; }
                else                { s_nsel = cum;         s_cbin = v; }
                hit = true; break;
            }
        }
        if (!hit) { s_nsel = cum; s_cbin = 255; }   // nc < FAST_K: take all
    }
    __syncthreads();
    const int cbin = s_cbin;
    const int n_sel = s_nsel;

    // Compact the selected prefix set into fast_k.
#pragma unroll
    for (int p = 0; p < CAP / 256; ++p) {
        int i = t + p * 256;
        if (i < nc) {
            u64 k = key_s[i];
            u32 d = ONE_BITS - (u32)(k >> 32);
            u32 bin = d >> sh;
            if (bin > 255u) bin = 255u;
            if ((int)bin <= cbin) fast_k[atomicAdd(&s_cnt, 1)] = k;
        }
    }
    __syncthreads();

    // Rank-order (replaces bitonic): each thread owns 2 keys; rank = count of
    // larger keys (LDS broadcast loop, no barriers). Unique keys -> ranks are
    // a permutation of [0, n_sel). Decode straight into boxes[rank].
    {
        u64 k0 = fast_k[t], k1 = fast_k[t + 256];
        int r0 = 0, r1 = 0;
        for (int i = 0; i < n_sel; ++i) {
            u64 kv = fast_k[i];
            r0 += (kv > k0);
            r1 += (kv > k1);
        }
        if (t < n_sel)       boxes[r0] = decode_box(k0, b, anchors4, deltas4);
        if (t + 256 < n_sel) boxes[r1] = decode_box(k1, b, anchors4, deltas4);
    }
    __syncthreads();

    if (t < 64) {
        int np = wave_nms(boxes, n_sel, out4, t);
        bool success = (np == MOS) || (n_sel == nc);
        if (success)
            for (int i = np + t; i < MOS; i += 64)
                out4[i] = make_float4(0.f, 0.f, 0.f, 0.f);
        if (t == 0) s_flag = success ? 1 : 0;
    }
    __syncthreads();
    if (s_flag) return;

    // ---------- Fallback: full sort of all candidates (rare by data) --------
    for (int k = 2; k <= CAP; k <<= 1) {
        for (int j = k >> 1; j > 0; j >>= 1) {
            for (int i = t; i < CAP; i += 256) {
                int ix = i ^ j;
                if (ix > i) {
                    u64 a = key_s[i], c = key_s[ix];
                    bool up = ((i & k) == 0);
                    if (up ? (a < c) : (a > c)) { key_s[i] = c; key_s[ix] = a; }
                }
            }
            __syncthreads();
        }
    }
    const int nvalid = min(nc, PRE_NMS);
    for (int i = t; i < PRE_NMS; i += 256)
        boxes[i] = (i < nvalid) ? decode_box(key_s[i], b, anchors4, deltas4)
                                : make_float4(0.f, 0.f, 0.f, 0.f);
    __syncthreads();
    if (t < 64) {
        int np = wave_nms(boxes, nvalid, out4, t);
        for (int i = np + t; i < MOS; i += 64)
            out4[i] = make_float4(0.f, 0.f, 0.f, 0.f);
    }
}

extern "C" void kernel_launch(void* const* d_in, const int* in_sizes, int n_in,
                              void* d_out, int out_size, void* d_ws, size_t ws_size,
                              hipStream_t stream) {
    const float* score_map = (const float*)d_in[0];
    const float* delta_map = (const float*)d_in[1];
    const float* anchors   = (const float*)d_in[2];
    float* out = (float*)d_out;
    const int B = in_sizes[0] / NPB;   // 32

    char* ws = (char*)d_ws;
    int* bcnt = (int*)ws;                                  // B*NSLOT ints
    u64* keys = (u64*)(((uintptr_t)(ws + (size_t)B * NSLOT * 4) + 15) & ~(uintptr_t)15);

    spec_compact_kernel<<<dim3(NSLOT, B), 256, 0, stream>>>(
        (const uint4*)score_map, bcnt, keys);
    sort_nms_kernel<<<B, 256, 0, stream>>>(
        (const uint4*)score_map, delta_map, anchors, bcnt, keys, out);
}